// Round 28
// baseline (924.028 us; speedup 1.0000x reference)
//
#include <hip/hip_runtime.h>
#include <hip/hip_bf16.h>
#include <math.h>

#define R_TOT 16384      // B*L
#define LSEQ  4096
#define DMODEL 1024
#define NHEAD 8
#define DHEAD 128        // DK = DV
#define NCHUNK 128       // LSEQ/32

typedef __hip_bfloat16 bf16;
typedef short s8v __attribute__((ext_vector_type(8)));
typedef float f4v __attribute__((ext_vector_type(4)));

__device__ __forceinline__ float sigmoidf_(float x) { return 1.f / (1.f + expf(-x)); }
__device__ __forceinline__ unsigned short f2bf(float f) {
    unsigned u = __float_as_uint(f);
    u += 0x7fffu + ((u >> 16) & 1u);
    return (unsigned short)(u >> 16);
}
__device__ __forceinline__ float bf2f(unsigned short s) {
    return __uint_as_float(((unsigned)s) << 16);
}

// ---------------------------------------------------------------------------
// Fused input prep: job 0 (blocks [0,8192)) = hs fp32->bf16 cast;
// jobs 1.. (blocks [8192,14848)) = all 7 weight transpose-casts.
// ---------------------------------------------------------------------------
__global__ __launch_bounds__(256)
void prep_inputs(const float* __restrict__ hs, unsigned short* __restrict__ hsb,
                 const float* __restrict__ Wq, const float* __restrict__ Wk,
                 const float* __restrict__ Wv, const float* __restrict__ Wb,
                 const float* __restrict__ gw1, const float* __restrict__ Wo,
                 const float* __restrict__ gw2,
                 unsigned short* __restrict__ wqkvbt, unsigned short* __restrict__ gw1t,
                 unsigned short* __restrict__ wot, unsigned short* __restrict__ gw2t)
{
    int id = blockIdx.x;
    if (id < 8192) {
        size_t i = ((size_t)id * 256 + threadIdx.x) * 8;
        float4 a = ((const float4*)(hs + i))[0];
        float4 b = ((const float4*)(hs + i))[1];
        s8v o;
        o[0] = (short)f2bf(a.x); o[1] = (short)f2bf(a.y);
        o[2] = (short)f2bf(a.z); o[3] = (short)f2bf(a.w);
        o[4] = (short)f2bf(b.x); o[5] = (short)f2bf(b.y);
        o[6] = (short)f2bf(b.z); o[7] = (short)f2bf(b.w);
        *(s8v*)(hsb + i) = o;
        return;
    }
    id -= 8192;
    const float* W; unsigned short* Wt;
    int K, Kpad, N, Npad, gx;
    if (id < 3072) {
        int j = id >> 10; id &= 1023;
        W = (j == 0) ? Wq : (j == 1) ? Wk : Wv;
        Wt = wqkvbt + (size_t)j * 1024 * 1024;
        K = 1024; Kpad = 1024; N = 1024; Npad = 1024; gx = 32;
    } else if (id < 3200) {
        id -= 3072; W = Wb; Wt = wqkvbt + (size_t)3072 * 1024;
        K = 1024; Kpad = 1024; N = 8; Npad = 128; gx = 32;
    } else if (id < 5376) {
        id -= 3200; W = gw1; Wt = gw1t;
        K = 1056; Kpad = 1088; N = 2048; Npad = 2048; gx = 34;
    } else if (id < 6400) {
        id -= 5376; W = Wo; Wt = wot;
        K = 1024; Kpad = 1024; N = 1024; Npad = 1024; gx = 32;
    } else {
        id -= 6400; W = gw2; Wt = gw2t;
        K = 2048; Kpad = 2048; N = 32; Npad = 128; gx = 64;
    }
    const int kb = (id % gx) * 32, nb = (id / gx) * 32;

    __shared__ float t[32][33];
    const int tx = threadIdx.x & 31, ty = threadIdx.x >> 5;   // ty 0..7
    for (int i = ty; i < 32; i += 8) {
        int k = kb + i, n = nb + tx;
        t[i][tx] = (k < K && n < N) ? W[(size_t)k * N + n] : 0.f;
    }
    __syncthreads();
    for (int i = ty; i < 32; i += 8) {
        int n = nb + i, k = kb + tx;
        if (n < Npad && k < Kpad) Wt[(size_t)n * Kpad + k] = f2bf(t[tx][i]);
    }
}

// ---------------------------------------------------------------------------
// MFMA bf16 GEMM, BK=64 K-tiles (round-21 verified): 8 global_load_lds per
// wave per iter, 16 barriers. Linear LDS [128][64] with XOR involution
// swizzle (chunk ^= row&7) applied at BOTH stage-source and fragment-read.
// MODE 0: fp32 out  2: gelu(x+bias,tanh-form) -> bf16  3: p-gate fp32
// MODE 5: qkvb split -> bf16 q/k/v (col<3072) + sigmoid fp32 beta -> C3
// ---------------------------------------------------------------------------
template<int MODE>
__global__ __launch_bounds__(256)
void mgemm(const unsigned short* __restrict__ A, const unsigned short* __restrict__ A2,
           int Ksplit, int lda1, int lda2,
           const unsigned short* __restrict__ Bt,
           const float* __restrict__ bias, const float* __restrict__ aux,
           void* __restrict__ C0, void* __restrict__ C1, void* __restrict__ C2,
           void* __restrict__ C3,
           int M, int N, int K, int Nout)
{
    __shared__ __align__(16) unsigned short As[128 * 64];
    __shared__ __align__(16) unsigned short Bs[128 * 64];
    const int tid = threadIdx.x;
    const int nwg = gridDim.x * gridDim.y;
    const int bidf = blockIdx.y * gridDim.x + blockIdx.x;
    const int nb = (bidf & 7) * (nwg >> 3) + (bidf >> 3);
    const int m0 = (nb / gridDim.x) * 128, n0 = (nb % gridDim.x) * 128;
    const int l = tid & 63;
    const int wid = tid >> 6;
    const int wr = (tid >> 7) & 1, wc = (tid >> 6) & 1;

    const int srow = l >> 3;                      // row within 8-row group
    const int cgo  = (((l & 7) ^ srow) << 3);     // swizzled source chunk (shorts)
    const int fr = l & 15;

    const f4v zf = {0.f, 0.f, 0.f, 0.f};
    f4v acc[4][4];
#pragma unroll
    for (int i = 0; i < 4; ++i)
#pragma unroll
        for (int j = 0; j < 4; ++j) acc[i][j] = zf;

    const int nkt = K >> 6;
    for (int kt = 0; kt < nkt; ++kt) {
        const int k0 = kt << 6;
#pragma unroll
        for (int j = 0; j < 4; ++j) {
            const int g = wid * 4 + j;            // 16 groups of 8 rows
            const int row = g * 8 + srow;
            const unsigned short* srcA = (k0 < Ksplit)
                ? A  + (size_t)(m0 + row) * lda1 + (size_t)(k0 + cgo)
                : A2 + (size_t)(m0 + row) * lda2 + (size_t)(k0 - Ksplit + cgo);
            __builtin_amdgcn_global_load_lds(
                (const __attribute__((address_space(1))) unsigned int*)srcA,
                (__attribute__((address_space(3))) unsigned int*)&As[g * 512],
                16, 0, 0);
            const unsigned short* srcB = Bt + (size_t)(n0 + row) * K + (size_t)(k0 + cgo);
            __builtin_amdgcn_global_load_lds(
                (const __attribute__((address_space(1))) unsigned int*)srcB,
                (__attribute__((address_space(3))) unsigned int*)&Bs[g * 512],
                16, 0, 0);
        }
        __syncthreads();
#pragma unroll
        for (int ks = 0; ks < 2; ++ks) {
            s8v af[4], bfr[4];
#pragma unroll
            for (int i = 0; i < 4; ++i) {
                const int rowA = wr * 64 + i * 16 + fr;
                const int rowB = wc * 64 + i * 16 + fr;
                const int gch = (l >> 4) + ks * 4;            // global chunk 0..7
                af[i]  = *(const s8v*)&As[rowA * 64 + ((gch ^ (rowA & 7)) << 3)];
                bfr[i] = *(const s8v*)&Bs[rowB * 64 + ((gch ^ (rowB & 7)) << 3)];
            }
#pragma unroll
            for (int i = 0; i < 4; ++i)
#pragma unroll
                for (int j = 0; j < 4; ++j)
                    acc[i][j] = __builtin_amdgcn_mfma_f32_16x16x32_bf16(af[i], bfr[j], acc[i][j], 0, 0, 0);
        }
        __syncthreads();
    }
    const int fq4 = (l >> 4) * 4;
#pragma unroll
    for (int i = 0; i < 4; ++i) {
#pragma unroll
        for (int j = 0; j < 4; ++j) {
            int col = n0 + wc * 64 + j * 16 + fr;
            if (MODE == 3 && col >= Nout) continue;
#pragma unroll
            for (int q = 0; q < 4; ++q) {
                int row = m0 + wr * 64 + i * 16 + fq4 + q;
                float x = acc[i][j][q];
                if (MODE == 2) {
                    x += bias[col];
                    float x3 = x * x * x;
                    float yv = 1.59576912f * fmaf(0.044715f, x3, x);
                    float e = expf(yv);
                    x = x * e / (1.f + e);
                    ((unsigned short*)C0)[(size_t)row * N + col] = f2bf(x);
                } else if (MODE == 3) {
                    x += bias[col];
                    x *= expf(-aux[col >> 2]);
                    x = 0.02f + 0.98f * sigmoidf_(x);
                    ((float*)C0)[(size_t)row * Nout + col] = x;
                } else if (MODE == 5) {
                    if (col < 3072) {
                        unsigned short* dst = (col < 1024) ? (unsigned short*)C0
                                            : ((col < 2048) ? (unsigned short*)C1
                                                            : (unsigned short*)C2);
                        dst[(size_t)row * 1024 + (col & 1023)] = f2bf(x);
                    } else if (col < 3080) {
                        ((float*)C3)[(size_t)row * 8 + (col - 3072)] = sigmoidf_(x);
                    }
                } else {
                    ((float*)C0)[(size_t)row * N + col] = x;
                }
            }
        }
    }
}

// ---------------------------------------------------------------------------
// Short causal conv (K=4) + SiLU, v2 (round-26 verified): 8 rows x 8 chans
// per thread, sliding-window register reuse. Fused q,k,v, non-aliased bufs.
// ---------------------------------------------------------------------------
__global__ __launch_bounds__(256)
void shortconv3(const unsigned short* __restrict__ xq, const unsigned short* __restrict__ xk,
                const unsigned short* __restrict__ xv,
                const float* __restrict__ wq, const float* __restrict__ wk,
                const float* __restrict__ wv,
                unsigned short* __restrict__ yq, unsigned short* __restrict__ yk,
                unsigned short* __restrict__ yv)
{
    const int job = blockIdx.x >> 10;
    const int bx  = blockIdx.x & 1023;
    const unsigned short* x = (job == 0) ? xq : (job == 1) ? xk : xv;
    const float* w          = (job == 0) ? wq : (job == 1) ? wk : wv;
    unsigned short* y       = (job == 0) ? yq : (job == 1) ? yk : yv;

    const int gidx = bx * 256 + threadIdx.x;      // 0..262143
    const int cchunk = gidx & 127;                // channel chunk (coalescing)
    const int rg = gidx >> 7;                     // row-group 0..2047
    const int c0 = cchunk * 8;
    const long r0 = (long)rg * 8;
    const int l0 = (int)(r0 & (LSEQ - 1));        // 0 only at sequence starts

    float4 wv8[8];
#pragma unroll
    for (int e = 0; e < 8; ++e) wv8[e] = ((const float4*)w)[c0 + e];

    const unsigned short* xp = x + r0 * DMODEL + c0;
    const s8v z8 = {0, 0, 0, 0, 0, 0, 0, 0};
    s8v xr[11];
    if (l0 > 0) {
#pragma unroll
        for (int i = 0; i < 11; ++i)
            xr[i] = *(const s8v*)&xp[(long)(i - 3) * DMODEL];
    } else {
        xr[0] = z8; xr[1] = z8; xr[2] = z8;
#pragma unroll
        for (int i = 3; i < 11; ++i)
            xr[i] = *(const s8v*)&xp[(long)(i - 3) * DMODEL];
    }

    unsigned short* yp = y + r0 * DMODEL + c0;
#pragma unroll
    for (int r = 0; r < 8; ++r) {
        float acc[8] = {0.f, 0.f, 0.f, 0.f, 0.f, 0.f, 0.f, 0.f};
#pragma unroll
        for (int j = 0; j < 4; ++j) {
            s8v v = xr[r + j];
#pragma unroll
            for (int e = 0; e < 8; ++e)
                acc[e] = fmaf(bf2f((unsigned short)v[e]), (&wv8[e].x)[j], acc[e]);
        }
        s8v o;
#pragma unroll
        for (int e = 0; e < 8; ++e) {
            float yv2 = acc[e] * sigmoidf_(acc[e]);
            o[e] = (short)f2bf(yv2);
        }
        *(s8v*)&yp[(long)r * DMODEL] = o;
    }
}

// ---------------------------------------------------------------------------
// Phase 1 prep (round-15 verified: blocked LDS solve, kn row write-through)
// ---------------------------------------------------------------------------
__global__ __launch_bounds__(256)
void chunk_prep3(const unsigned short* __restrict__ qconv, const unsigned short* __restrict__ kconv,
                 const unsigned short* __restrict__ vbf, const float* __restrict__ beta,
                 unsigned short* __restrict__ qe_out, unsigned short* __restrict__ kn_out,
                 bf16* __restrict__ wu, unsigned short* __restrict__ opre)
{
    const int bid = blockIdx.x;              // (b*8+h)*128 + c
    const int c = bid & 127, h = (bid >> 7) & 7, b = bid >> 10;
    const int tid = threadIdx.x;
    const int l = tid & 63, wid = tid >> 6;

    __shared__ __align__(16) unsigned short q_b[32 * 136];
    __shared__ __align__(16) unsigned short k_b[32 * 136];
    __shared__ __align__(16) unsigned short at_b[32 * 40];
    __shared__ float xs[32][257];            // solve state: [row][column(tid)]
    __shared__ __align__(16) float Am[32][36];
    __shared__ float betas_s[32];

    const size_t row0 = (size_t)b * LSEQ + (size_t)c * 32;
    const size_t base = row0 * DMODEL + (size_t)h * DHEAD;
    const f4v zf = {0.f, 0.f, 0.f, 0.f};
    const int li = tid >> 3, ld0 = (tid & 7) * 16;

    // ---- phase 0: load q,k rows (bf16, vectorized)
    {
        const unsigned short* gq = qconv + base + (size_t)li * DMODEL + ld0;
        const unsigned short* gk = kconv + base + (size_t)li * DMODEL + ld0;
        *(uint4*)&q_b[li * 136 + ld0]     = ((const uint4*)gq)[0];
        *(uint4*)&q_b[li * 136 + ld0 + 8] = ((const uint4*)gq)[1];
        *(uint4*)&k_b[li * 136 + ld0]     = ((const uint4*)gk)[0];
        *(uint4*)&k_b[li * 136 + ld0 + 8] = ((const uint4*)gk)[1];
    }
    if (tid < 32) betas_s[tid] = beta[(row0 + tid) * NHEAD + h];
    __syncthreads();

    // ---- phase 1: l2norm rows of q,k (re-read LDS)
    {
        float sq = 0.f, sk = 0.f;
#pragma unroll
        for (int e = 0; e < 8; ++e) {
            unsigned uq = *(const unsigned*)&q_b[li * 136 + ld0 + e * 2];
            unsigned uk = *(const unsigned*)&k_b[li * 136 + ld0 + e * 2];
            float q0 = bf2f((unsigned short)uq), q1 = bf2f((unsigned short)(uq >> 16));
            float k0 = bf2f((unsigned short)uk), k1 = bf2f((unsigned short)(uk >> 16));
            sq = fmaf(q0, q0, fmaf(q1, q1, sq));
            sk = fmaf(k0, k0, fmaf(k1, k1, sk));
        }
#pragma unroll
        for (int m = 1; m < 8; m <<= 1) { sq += __shfl_xor(sq, m); sk += __shfl_xor(sk, m); }
        float rq = rsqrtf(sq + 1e-6f), rk = rsqrtf(sk + 1e-6f);
#pragma unroll
        for (int e = 0; e < 8; ++e) {
            unsigned uq = *(const unsigned*)&q_b[li * 136 + ld0 + e * 2];
            unsigned uk = *(const unsigned*)&k_b[li * 136 + ld0 + e * 2];
            unsigned pq = (unsigned)f2bf(bf2f((unsigned short)uq) * rq)
                        | ((unsigned)f2bf(bf2f((unsigned short)(uq >> 16)) * rq) << 16);
            unsigned pk = (unsigned)f2bf(bf2f((unsigned short)uk) * rk)
                        | ((unsigned)f2bf(bf2f((unsigned short)(uk >> 16)) * rk) << 16);
            *(unsigned*)&q_b[li * 136 + ld0 + e * 2] = pq;
            *(unsigned*)&k_b[li * 136 + ld0 + e * 2] = pk;
        }
    }
    __syncthreads();

    // ---- phase 2: kn write-through (vectorized)
    {
        unsigned short* gk = kn_out + base + (size_t)li * DMODEL + ld0;
        ((uint4*)gk)[0] = *(const uint4*)&k_b[li * 136 + ld0];
        ((uint4*)gk)[1] = *(const uint4*)&k_b[li * 136 + ld0 + 8];
    }

    // ---- phase 3: Am, at via MFMA (wave wid -> 16x16 tile (tr,tc))
    {
        const int tr = wid >> 1, tc = wid & 1;
        const int fr = l & 15, ko = (l >> 4) * 8;
        f4v accA = zf, accT = zf;
#pragma unroll
        for (int kt = 0; kt < 4; ++kt) {
            s8v ka  = *(const s8v*)&k_b[(tr * 16 + fr) * 136 + kt * 32 + ko];
            s8v qa  = *(const s8v*)&q_b[(tr * 16 + fr) * 136 + kt * 32 + ko];
            s8v kb2 = *(const s8v*)&k_b[(tc * 16 + fr) * 136 + kt * 32 + ko];
            accA = __builtin_amdgcn_mfma_f32_16x16x32_bf16(ka, kb2, accA, 0, 0, 0);
            accT = __builtin_amdgcn_mfma_f32_16x16x32_bf16(qa, kb2, accT, 0, 0, 0);
        }
        const int jloc = tc * 16 + fr;
#pragma unroll
        for (int q = 0; q < 4; ++q) {
            int iloc = tr * 16 + (l >> 4) * 4 + q;
            Am[iloc][jloc] = (iloc > jloc) ? betas_s[iloc] * accA[q] : 0.f;
            at_b[iloc * 40 + jloc] = f2bf((iloc >= jloc) ? accT[q] : 0.f);
        }
    }
    __syncthreads();

    // ---- phase 4: blocked forward substitution; thread t = one column.
    {
        const int t = tid;
        if (t < 128) {
#pragma unroll 1
            for (int i = 0; i < 32; ++i)
                xs[i][t] = betas_s[i] * bf2f(vbf[base + (size_t)i * DMODEL + t]);
        } else {
            const int d = t - 128;
#pragma unroll 1
            for (int i = 0; i < 32; ++i)
                xs[i][t] = betas_s[i] * bf2f(k_b[i * 136 + d]);
        }
#pragma unroll 1
        for (int b8 = 0; b8 < 4; ++b8) {
            const int i0 = b8 * 8;
            float xl[8];
#pragma unroll
            for (int j = 0; j < 8; ++j) xl[j] = xs[i0 + j][t];
            // apply previous blocks
#pragma unroll 1
            for (int m = 0; m < i0; m += 4) {
                float xm0 = xs[m][t],     xm1 = xs[m + 1][t];
                float xm2 = xs[m + 2][t], xm3 = xs[m + 3][t];
#pragma unroll
                for (int j = 0; j < 8; ++j) {
                    float4 am = *(const float4*)&Am[i0 + j][m];
                    xl[j] -= am.x * xm0 + am.y * xm1 + am.z * xm2 + am.w * xm3;
                }
            }
            // in-register 8x8 triangle
#pragma unroll
            for (int j = 1; j < 8; ++j) {
                float s = 0.f;
#pragma unroll
                for (int jj = 0; jj < j; ++jj) s = fmaf(Am[i0 + j][i0 + jj], xl[jj], s);
                xl[j] -= s;
            }
#pragma unroll
            for (int j = 0; j < 8; ++j) xs[i0 + j][t] = xl[j];
        }
        // global w|u writeback (reads own column: conflict-free)
        const size_t tb = (size_t)bid * 8192;
        if (t < 128) {
#pragma unroll 1
            for (int i = 0; i < 32; ++i)
                wu[tb + 4096 + i * 128 + t] = __float2bfloat16(xs[i][t]);
        } else {
            const int d = t - 128;
#pragma unroll 1
            for (int i = 0; i < 32; ++i)
                wu[tb + i * 128 + d] = __float2bfloat16(xs[i][t]);
        }
    }
    __syncthreads();

    // ---- phase 5: qe = qn - at@w ; o_pre = at@u (B-fragments built from xs)
    {
        const int fr = l & 15, ko = (l >> 4) * 8;
        s8v bw0, bw1, bu0, bu1;
#pragma unroll
        for (int e = 0; e < 8; ++e) {
            bw0[e] = (short)f2bf(xs[ko + e][128 + wid * 32 + fr]);
            bw1[e] = (short)f2bf(xs[ko + e][128 + wid * 32 + 16 + fr]);
            bu0[e] = (short)f2bf(xs[ko + e][wid * 32 + fr]);
            bu1[e] = (short)f2bf(xs[ko + e][wid * 32 + 16 + fr]);
        }
#pragma unroll
        for (int rt = 0; rt < 2; ++rt) {
            s8v a = *(const s8v*)&at_b[(rt * 16 + fr) * 40 + ko];
            f4v qw0 = __builtin_amdgcn_mfma_f32_16x16x32_bf16(a, bw0, zf, 0, 0, 0);
            f4v qw1 = __builtin_amdgcn_mfma_f32_16x16x32_bf16(a, bw1, zf, 0, 0, 0);
            f4v ou0 = __builtin_amdgcn_mfma_f32_16x16x32_bf16(a, bu0, zf, 0, 0, 0);
            f4v ou1 = __builtin_amdgcn_mfma_f32_16x16x32_bf16(a, bu1, zf, 0, 0, 0);
#pragma unroll
            for (int q = 0; q < 4; ++q) {
                const int i = rt * 16 + (l >> 4) * 4 + q;
                {
                    const int d = wid * 32 + fr;
                    size_t g = base + (size_t)i * DMODEL + d;
                    qe_out[g] = f2bf(bf2f(q_b[i * 136 + d]) - qw0[q]);
                    opre[g]   = f2bf(ou0[q]);
                }
                {
                    const int d = wid * 32 + 16 + fr;
                    size_t g = base + (size_t)i * DMODEL + d;
                    qe_out[g] = f2bf(bf2f(q_b[i * 136 + d]) - qw1[q]);
                    opre[g]   = f2bf(ou1[q]);
                }
            }
        }
    }
}

// ---------------------------------------------------------------------------
// Phase 2: MFMA state scan, 8 waves (512 thr), role-split (round-19/21
// verified best). knT transpose write uses compile-time e indexing +
// pcolp XOR swizzle; phase-B read compensates with koff^sw.
// ---------------------------------------------------------------------------
__global__ __launch_bounds__(512)
void delta_scan5(const unsigned short* __restrict__ qe, const unsigned short* __restrict__ kn,
                 const bf16* __restrict__ wu, bf16* __restrict__ delta,
                 const float* __restrict__ ret)
{
    const int bid0 = blockIdx.x;
    const int dvs = (bid0 >> 3) & 7;                      // dv-slice
    const int bh  = ((bid0 >> 6) << 3) | (bid0 & 7);      // xcd-stable bh
    const int h = bh & 7, b = bh >> 3;
    const int tid = threadIdx.x;
    const int l = tid & 63, wid = tid >> 6;

    __shared__ __align__(16) unsigned short qe_b[2][32 * 136];
    __shared__ __align__(16) unsigned short w_b [2][32 * 136];
    __shared__ __align__(16) unsigned short knT [2][128 * 40];
    __shared__ __align__(16) unsigned short St_b[16 * 136];
    __shared__ __align__(16) unsigned short uaT [16 * 40];
    __shared__ float us_s[2][32][18], ops_s[2][32][18];

    const float lam = 0.6f + 0.4f * sigmoidf_(ret[h]);

    for (int i = tid; i < 16 * 136; i += 512) St_b[i] = 0;

    // producer-thread geometry (tid >= 256)
    const int pti = tid & 255;
    const int pli = pti >> 3, pld0 = (pti & 7) * 16;
    const int piu = pti >> 3, ptu = (pti & 7) * 2;
    const int pkswz = ((pld0 >> 4) & 3) << 3;
    const int pcolp = pli ^ pkswz;
    const size_t headoff = (size_t)h * DHEAD;

    const f4v zf = {0.f, 0.f, 0.f, 0.f};
    f4v Sacc = zf;                      // this wave's S d-tile (d0 = wid*16)

    uint4 pq[2], pk[2], pw[2];
    unsigned puv, pov;

#define ISSUE(cc)  {                                                                        \
        size_t rb = ((size_t)b * LSEQ + (size_t)(cc) * 32);                                 \
        const unsigned short* gq = qe + (rb + pli) * DMODEL + headoff + pld0;               \
        const unsigned short* gk = kn + (rb + pli) * DMODEL + headoff + pld0;               \
        pq[0] = ((const uint4*)gq)[0]; pq[1] = ((const uint4*)gq)[1];                       \
        pk[0] = ((const uint4*)gk)[0]; pk[1] = ((const uint4*)gk)[1];                       \
        size_t tb = ((size_t)bh * NCHUNK + (cc)) * 8192;                                    \
        const uint4* gw = (const uint4*)(wu + tb + pli * 128 + pld0);                       \
        pw[0] = gw[0]; pw[1] = gw[1];                                                       \
        puv = *(const unsigned*)(wu + tb + 4096 + piu * 128 + dvs * 16 + ptu);              \
        pov = *(const unsigned*)(delta + (rb + piu) * DMODEL + headoff + dvs * 16 + ptu);   \
    }

#define UNPACK(bf)  {                                                                       \
        *(uint4*)&qe_b[bf][pli * 136 + pld0]     = pq[0];                                   \
        *(uint4*)&qe_b[bf][pli * 136 + pld0 + 8] = pq[1];                                   \
        const unsigned short* pks = (const unsigned short*)&pk[0];                          \
        _Pragma("unroll")                                                                   \
        for (int e = 0; e < 16; ++e)                                                        \
            knT[bf][(pld0 + e) * 40 + pcolp] = pks[e];                                      \
        *(uint4*)&w_b[bf][pli * 136 + pld0]     = pw[0];                                    \
        *(uint4*)&w_b[bf][pli * 136 + pld0 + 8] = pw[1];                                    \
        us_s[bf][piu][ptu]      = bf2f((unsigned short)puv);                                \
        us_s[bf][piu][ptu + 1]  = bf2f((unsigned short)(puv >> 16));                        \
        ops_s[bf][piu][ptu]     = bf2f((unsigned short)pov);                                \
        ops_s[bf][piu][ptu + 1] = bf2f((unsigned short)(pov >> 16));                        \
    }

    if (tid >= 256) {
        ISSUE(0);
        UNPACK(0);
        ISSUE(1);
    }
    __syncthreads();

    for (int c = 0; c < NCHUNK; ++c) {
        const int cur = c & 1;

        if (wid < 4) {
            // ---- phase A (consumers): w0,w1 -> ua = u - w@S ; w2,w3 -> o = opre + qe@S
            const int half = wid & 1;
            const int arow = half * 16 + (l & 15);
            const int koff = (l >> 4) * 8;
            const unsigned short* ab = (wid < 2) ? w_b[cur] : qe_b[cur];
            f4v a0v = zf, a1v = zf;
#pragma unroll
            for (int kt = 0; kt < 2; ++kt) {
                s8v af  = *(const s8v*)&ab[arow * 136 + kt * 32 + koff];
                s8v bf_ = *(const s8v*)&St_b[(l & 15) * 136 + kt * 32 + koff];
                a0v = __builtin_amdgcn_mfma_f32_16x16x32_bf16(af, bf_, a0v, 0, 0, 0);
            }
#pragma unroll
            for (int kt = 2; kt < 4; ++kt) {
                s8v af  = *(const s8v*)&ab[arow * 136 + kt * 32 + koff];
                s8v bf_ = *(const s8v*)&St_b[(l & 15) * 136 + kt * 32 + koff];
                a1v = __builtin_amdgcn_mfma_f32_16x16x32_bf16(af, bf_, a1v, 0, 0, 0);
            }
            const int ib = half * 16 + ((l >> 4) << 2);
            const int t = l & 15;
            if (wid < 2) {
#pragma unroll
                for (int q = 0; q < 4; ++q) {
                    float v = us_s[cur][ib + q][t] - (a0v[q] + a1v[q]);
                    uaT[t * 40 + ib + q] = f2bf(v);
                }
            } else {
                size_t rb = (size_t)b * LSEQ + (size_t)c * 32;
#pragma unroll
                for (int q = 0; q < 4; ++q) {
                    float v = ops_s[cur][ib + q][t] + (a0v[q] + a1v[q]);
                    delta[(rb + ib + q) * DMODEL + headoff + dvs * 16 + t] = __float2bfloat16(v);
                }
            }
        } else {
            // ---- producers: prefetch next chunk into the other buffer
            if (c + 1 < NCHUNK) UNPACK(cur ^ 1);
            if (c + 2 < NCHUNK) ISSUE(c + 2);
        }
        __syncthreads();

        // ---- phase B (all 8 waves): Sacc = lam*Sacc + uaT @ knT ; export St_b
        {
#pragma unroll
            for (int q = 0; q < 4; ++q) Sacc[q] *= lam;
            const int koff = (l >> 4) * 8;
            const int sw = (wid & 3) << 3;         // (d>>4)&3 for d = wid*16+(l&15)
            s8v af = *(const s8v*)&uaT[(l & 15) * 40 + koff];
            const int d0 = wid * 16;
            s8v b0 = *(const s8v*)&knT[cur][(d0 + (l & 15)) * 40 + (koff ^ sw)];
            Sacc = __builtin_amdgcn_mfma_f32_16x16x32_bf16(af, b0, Sacc, 0, 0, 0);

            const int tr = (l >> 4) << 2;
#pragma unroll
            for (int q = 0; q < 4; ++q)
                St_b[(tr + q) * 136 + d0 + (l & 15)] = f2bf(Sacc[q]);
        }
        __syncthreads();
    }
#undef ISSUE
#undef UNPACK
}

// ---------------------------------------------------------------------------
// FIR computed once, LDS-tiled, WITH FUSED STATS: per-row means of fs, fl,
// dlt, v reduced in-wave (one wave owns all 128 channels of its 8 rows).
// ---------------------------------------------------------------------------
__global__ __launch_bounds__(256)
void fir_compute(const unsigned short* __restrict__ v,
                 const float* __restrict__ wshort, const float* __restrict__ wlong,
                 const unsigned short* __restrict__ dlt,
                 unsigned short* __restrict__ fso, unsigned short* __restrict__ flo,
                 unsigned short* __restrict__ stats)
{
    const int lt = blockIdx.x, h = blockIdx.y, b = blockIdx.z;
    const int tid = threadIdx.x;
    __shared__ unsigned short vt[190 * 128];
    __shared__ float wl[63 * 128];
    __shared__ float w3[3 * 128];

    for (int i = tid; i < 63 * 128; i += 256) {
        int j = i >> 7, d = i & 127;
        wl[i] = wlong[((size_t)h * 128 + d) * 63 + j];
    }
    for (int i = tid; i < 3 * 128; i += 256) {
        int j = i >> 7, d = i & 127;
        w3[i] = wshort[((size_t)h * 128 + d) * 3 + j];
    }
    const size_t vbase = ((size_t)b * LSEQ) * DMODEL + (size_t)h * DHEAD;
    const int l0 = lt * 128;
    const s8v z8 = {0, 0, 0, 0, 0, 0, 0, 0};
    for (int i = tid; i < 190 * 16; i += 256) {
        int row = i >> 4, dblk = (i & 15) * 8;
        int gl = l0 - 62 + row;
        s8v val = z8;
        if (gl >= 0) val = *(const s8v*)&v[vbase + (size_t)gl * DMODEL + dblk];
        *(s8v*)&vt[row * 128 + dblk] = val;
    }
    __syncthreads();

    const int dp = (tid & 63) * 2, lg = tid >> 6;
    const int lane = tid & 63;
    const float inv = 1.f / 128.f;
    for (int lc = 0; lc < 4; ++lc) {
        const int lb = lg * 32 + lc * 8;
        float a0[8], a1[8], s0[8], s1[8];
#pragma unroll
        for (int li = 0; li < 8; ++li) { a0[li] = a1[li] = s0[li] = s1[li] = 0.f; }
        for (int j = 0; j < 63; ++j) {
            float w0 = wl[j * 128 + dp], w1 = wl[j * 128 + dp + 1];
#pragma unroll
            for (int li = 0; li < 8; ++li) {
                unsigned vv = *(const unsigned*)&vt[(lb + li + j) * 128 + dp];
                a0[li] = fmaf(bf2f((unsigned short)vv), w0, a0[li]);
                a1[li] = fmaf(bf2f((unsigned short)(vv >> 16)), w1, a1[li]);
            }
        }
#pragma unroll
        for (int j = 0; j < 3; ++j) {
            float w0 = w3[j * 128 + dp], w1 = w3[j * 128 + dp + 1];
#pragma unroll
            for (int li = 0; li < 8; ++li) {
                unsigned vv = *(const unsigned*)&vt[(lb + li + 60 + j) * 128 + dp];
                s0[li] = fmaf(bf2f((unsigned short)vv), w0, s0[li]);
                s1[li] = fmaf(bf2f((unsigned short)(vv >> 16)), w1, s1[li]);
            }
        }
        const size_t ob = ((size_t)b * LSEQ + l0) * DMODEL + (size_t)h * DHEAD + dp;
#pragma unroll
        for (int li = 0; li < 8; ++li) {
            unsigned pf = (unsigned)f2bf(a0[li]) | ((unsigned)f2bf(a1[li]) << 16);
            unsigned ps = (unsigned)f2bf(s0[li]) | ((unsigned)f2bf(s1[li]) << 16);
            *(unsigned*)&flo[ob + (size_t)(lb + li) * DMODEL] = pf;
            *(unsigned*)&fso[ob + (size_t)(lb + li) * DMODEL] = ps;
        }
        // ---- fused stats: per-row sums across this wave's 64 lanes
#pragma unroll
        for (int li = 0; li < 8; ++li) {
            float sfs = s0[li] + s1[li];
            float sfl = a0[li] + a1[li];
            unsigned vv = *(const unsigned*)&vt[(lb + li + 62) * 128 + dp];
            float sv = bf2f((unsigned short)vv) + bf2f((unsigned short)(vv >> 16));
            unsigned dd = *(const unsigned*)&dlt[ob + (size_t)(lb + li) * DMODEL];
            float sd = bf2f((unsigned short)dd) + bf2f((unsigned short)(dd >> 16));
#pragma unroll
            for (int m = 1; m < 64; m <<= 1) {
                sfs += __shfl_xor(sfs, m); sfl += __shfl_xor(sfl, m);
                sd  += __shfl_xor(sd, m);  sv  += __shfl_xor(sv, m);
            }
            if (lane == 0) {
                const size_t r = (size_t)b * LSEQ + l0 + lb + li;
                stats[r * 64 + 0  + h] = f2bf(sfs * inv);
                stats[r * 64 + 8  + h] = f2bf(sfl * inv);
                stats[r * 64 + 16 + h] = f2bf(sd * inv);
                stats[r * 64 + 24 + h] = f2bf(sv * inv);
            }
        }
    }
}

// ---------------------------------------------------------------------------
// Combine + RMS norm; bf16 output (feeds final MFMA GEMM)
// ---------------------------------------------------------------------------
__global__ __launch_bounds__(256)
void combine2(const unsigned short* __restrict__ fs, const unsigned short* __restrict__ fl,
              const unsigned short* __restrict__ dlt, const unsigned short* __restrict__ v,
              const float* __restrict__ p, const float* __restrict__ onw,
              unsigned short* __restrict__ on)
{
    const int rh = blockIdx.x * 4 + (threadIdx.x >> 6);
    const int lane = threadIdx.x & 63;
    const int r = rh >> 3, h = rh & 7;
    const size_t base = (size_t)r * DMODEL + (size_t)h * DHEAD + lane * 2;
    unsigned ua = *(const unsigned*)(fs + base);
    unsigned ub = *(const unsigned*)(fl + base);
    unsigned uc = *(const unsigned*)(dlt + base);
    unsigned ud = *(const unsigned*)(v + base);
    const float* pp = p + (size_t)r * 32 + h * 4;
    float p0 = pp[0], p1 = pp[1], p2 = pp[2], p3 = pp[3];
    float ox = p0 * bf2f((unsigned short)ua) + p1 * bf2f((unsigned short)ub)
             + p2 * bf2f((unsigned short)uc) + p3 * bf2f((unsigned short)ud);
    float oy = p0 * bf2f((unsigned short)(ua >> 16)) + p1 * bf2f((unsigned short)(ub >> 16))
             + p2 * bf2f((unsigned short)(uc >> 16)) + p3 * bf2f((unsigned short)(ud >> 16));
    float ss = ox * ox + oy * oy;
#pragma unroll
    for (int m = 1; m < 64; m <<= 1) ss += __shfl_xor(ss, m);
    float sc = rsqrtf(ss * (1.f / 128.f) + 1e-5f);
    unsigned pw = (unsigned)f2bf(ox * sc * onw[lane * 2])
                | ((unsigned)f2bf(oy * sc * onw[lane * 2 + 1]) << 16);
    *(unsigned*)(on + base) = pw;
}

// ---------------------------------------------------------------------------
// Workspace (~203 MB), RACE-FREE. hdn spans B.hi+C.lo (contiguous 64MB);
// onb in B.hi after hdn dies. fir now also emits stats (fused).
//  A.lo: qpb -> wu.lo -> fs          A.hi: kpb -> wu.hi -> fl
//  B.lo: vpb -> opre/delta           B.hi: qcb/qe -> hdn[0:8192) -> o_norm
//  C.lo: kcb/kn -> hdn[8192:16384)   C.hi: vbf (lives to combine)
//  O.lo(d_out): hsb bf16             O.hi: wqkvbt  -> final out fp32 (full)
// ---------------------------------------------------------------------------
extern "C" void kernel_launch(void* const* d_in, const int* in_sizes, int n_in,
                              void* d_out, int out_size, void* d_ws, size_t ws_size,
                              hipStream_t stream)
{
    const float* hs   = (const float*)d_in[0];
    const float* Wq   = (const float*)d_in[1];
    const float* Wk   = (const float*)d_in[2];
    const float* Wv   = (const float*)d_in[3];
    const float* Wb   = (const float*)d_in[4];
    const float* cqw  = (const float*)d_in[5];
    const float* ckw  = (const float*)d_in[6];
    const float* cvw  = (const float*)d_in[7];
    const float* ret  = (const float*)d_in[8];
    const float* fsw  = (const float*)d_in[9];
    const float* flw  = (const float*)d_in[10];
    const float* gw1  = (const float*)d_in[11];
    const float* gb1  = (const float*)d_in[12];
    const float* gw2  = (const float*)d_in[13];
    const float* gb2  = (const float*)d_in[14];
    const float* ltmp = (const float*)d_in[15];
    const float* onw  = (const float*)d_in[16];
    const float* Wo   = (const float*)d_in[17];
    float* out = (float*)d_out;

    char* wsp = (char*)d_ws;
    size_t off = 0;
    auto alloc = [&](size_t nbytes) -> void* {
        void* pt = (void*)(wsp + off);
        off += ((nbytes + 255) / 256) * 256;
        return pt;
    };
    const int R = R_TOT;
    const size_t HALF = (size_t)R * DMODEL;        // elements per 32MB half
    float* bufA  = (float*)alloc(HALF * 4);
    float* bufB  = (float*)alloc(HALF * 4);
    float* bufC  = (float*)alloc(HALF * 4);
    float* beta  = (float*)alloc((size_t)R * NHEAD * 4);
    unsigned short* statsb = (unsigned short*)alloc((size_t)R * 64 * 2);
    float* pbuf  = (float*)alloc((size_t)R * 32 * 4);
    unsigned short* gw1t = (unsigned short*)alloc((size_t)2048 * 1088 * 2);
    unsigned short* wot  = (unsigned short*)alloc((size_t)1024 * 1024 * 2);
    unsigned short* gw2t = (unsigned short*)alloc((size_t)128 * 2048 * 2);

    unsigned short* Alo = (unsigned short*)bufA;  unsigned short* Ahi = Alo + HALF;
    unsigned short* Blo = (unsigned short*)bufB;  unsigned short* Bhi = Blo + HALF;
    unsigned short* Clo = (unsigned short*)bufC;  unsigned short* Chi = Clo + HALF;
    unsigned short* Olo = (unsigned short*)d_out; unsigned short* Ohi = Olo + HALF;

    unsigned short* hsb    = Olo;                 // hs bf16
    unsigned short* wqkvbt = Ohi;                 // 3200x1024 bf16 = 6.6MB
    unsigned short* qpb = Alo, *kpb = Ahi, *vpb = Blo;
    unsigned short* qcb = Bhi, *kcb = Clo, *vbf = Chi;   // conv out: no aliasing
    bf16* wu = (bf16*)bufA;                       // qpb/kpb dead after conv
    unsigned short* dlt = Blo;                    // opre -> delta (vpb dead)
    unsigned short* fsb = Alo, *flb = Ahi;        // wu dead after scan
    unsigned short* hdnb = Bhi;                   // gate1 out: 64MB span B.hi+C.lo
    unsigned short* onb = Bhi;                    // o_norm bf16 (hdn dead after gate2)
    (void)ws_size; (void)in_sizes; (void)n_in; (void)out_size;

    dim3 blk(256);
    // 0+1. hs cast + all weight transposes in ONE launch (14848 blocks)
    prep_inputs<<<14848, blk, 0, stream>>>(hs, hsb, Wq, Wk, Wv, Wb, gw1, Wo, gw2,
                                           wqkvbt, gw1t, wot, gw2t);

    // 2. fused qkv+beta projection (bf16 A; q/k/v bf16, beta fp32 via C3)
    mgemm<5><<<dim3(25, 128), blk, 0, stream>>>(hsb, nullptr, 1 << 30, DMODEL, 0,
                                                wqkvbt, nullptr, nullptr,
                                                qpb, kpb, vpb, beta, R, 3200, 1024, 0);
    // 4. short conv + silu v2 (8 rows/thread sliding window; 3x1024 blocks)
    shortconv3<<<3 * 1024, blk, 0, stream>>>(qpb, kpb, vpb, cqw, ckw, cvw,
                                             qcb, kcb, vbf);
    // 5/6. delta rule (scan 8-wave role-split)
    chunk_prep3<<<4096, blk, 0, stream>>>(qcb, kcb, vbf, beta, qcb, kcb, wu, dlt);
    delta_scan5<<<256, dim3(512), 0, stream>>>(qcb, kcb, wu, (bf16*)dlt, ret);
    // 7+8. FIR + fused stats (wu dead -> bufA holds fs|fl; stats stride 64)
    fir_compute<<<dim3(32, 8, 4), blk, 0, stream>>>(vbf, fsw, flw, dlt, fsb, flb, statsb);
    // 9. gate MLP, single launch each (hdn = 64MB contiguous B.hi+C.lo)
    mgemm<2><<<dim3(16, 128), blk, 0, stream>>>(hsb, statsb,
                                                1024, DMODEL, 64, gw1t, gb1, nullptr,
                                                hdnb, nullptr, nullptr, nullptr,
                                                R, 2048, 1088, 0);
    mgemm<3><<<dim3(1, 128), blk, 0, stream>>>(hdnb, nullptr, 1 << 30, 2048, 0,
                                               gw2t, gb2, ltmp,
                                               pbuf, nullptr, nullptr, nullptr,
                                               R, 128, 2048, 32);
    // 10. combine + RMS norm -> o_norm bf16 (B.hi; hdn dead after gate2)
    combine2<<<32768, blk, 0, stream>>>(fsb, flb, dlt, vbf, pbuf, onw, onb);
    // 11. final projection -> d_out fp32 (hsb/wqkvbt dead)
    mgemm<0><<<dim3(8, 128), blk, 0, stream>>>(onb, nullptr, 1 << 30, DMODEL, 0,
                                               wot, nullptr, nullptr,
                                               out, nullptr, nullptr, nullptr, R, 1024, 1024, 0);
}

// Round 29
// 887.381 us; speedup vs baseline: 1.0413x; 1.0413x over previous
//
#include <hip/hip_runtime.h>
#include <hip/hip_bf16.h>
#include <math.h>

#define R_TOT 16384      // B*L
#define LSEQ  4096
#define DMODEL 1024
#define NHEAD 8
#define DHEAD 128        // DK = DV
#define NCHUNK 128       // LSEQ/32

typedef __hip_bfloat16 bf16;
typedef short s8v __attribute__((ext_vector_type(8)));
typedef float f4v __attribute__((ext_vector_type(4)));

__device__ __forceinline__ float sigmoidf_(float x) { return 1.f / (1.f + expf(-x)); }
__device__ __forceinline__ unsigned short f2bf(float f) {
    unsigned u = __float_as_uint(f);
    u += 0x7fffu + ((u >> 16) & 1u);
    return (unsigned short)(u >> 16);
}
__device__ __forceinline__ float bf2f(unsigned short s) {
    return __uint_as_float(((unsigned)s) << 16);
}

// ---------------------------------------------------------------------------
// Fused input prep: job 0 (blocks [0,8192)) = hs fp32->bf16 cast;
// jobs 1.. (blocks [8192,14848)) = all 7 weight transpose-casts.
// ---------------------------------------------------------------------------
__global__ __launch_bounds__(256)
void prep_inputs(const float* __restrict__ hs, unsigned short* __restrict__ hsb,
                 const float* __restrict__ Wq, const float* __restrict__ Wk,
                 const float* __restrict__ Wv, const float* __restrict__ Wb,
                 const float* __restrict__ gw1, const float* __restrict__ Wo,
                 const float* __restrict__ gw2,
                 unsigned short* __restrict__ wqkvbt, unsigned short* __restrict__ gw1t,
                 unsigned short* __restrict__ wot, unsigned short* __restrict__ gw2t)
{
    int id = blockIdx.x;
    if (id < 8192) {
        size_t i = ((size_t)id * 256 + threadIdx.x) * 8;
        float4 a = ((const float4*)(hs + i))[0];
        float4 b = ((const float4*)(hs + i))[1];
        s8v o;
        o[0] = (short)f2bf(a.x); o[1] = (short)f2bf(a.y);
        o[2] = (short)f2bf(a.z); o[3] = (short)f2bf(a.w);
        o[4] = (short)f2bf(b.x); o[5] = (short)f2bf(b.y);
        o[6] = (short)f2bf(b.z); o[7] = (short)f2bf(b.w);
        *(s8v*)(hsb + i) = o;
        return;
    }
    id -= 8192;
    const float* W; unsigned short* Wt;
    int K, Kpad, N, Npad, gx;
    if (id < 3072) {
        int j = id >> 10; id &= 1023;
        W = (j == 0) ? Wq : (j == 1) ? Wk : Wv;
        Wt = wqkvbt + (size_t)j * 1024 * 1024;
        K = 1024; Kpad = 1024; N = 1024; Npad = 1024; gx = 32;
    } else if (id < 3200) {
        id -= 3072; W = Wb; Wt = wqkvbt + (size_t)3072 * 1024;
        K = 1024; Kpad = 1024; N = 8; Npad = 128; gx = 32;
    } else if (id < 5376) {
        id -= 3200; W = gw1; Wt = gw1t;
        K = 1056; Kpad = 1088; N = 2048; Npad = 2048; gx = 34;
    } else if (id < 6400) {
        id -= 5376; W = Wo; Wt = wot;
        K = 1024; Kpad = 1024; N = 1024; Npad = 1024; gx = 32;
    } else {
        id -= 6400; W = gw2; Wt = gw2t;
        K = 2048; Kpad = 2048; N = 32; Npad = 128; gx = 64;
    }
    const int kb = (id % gx) * 32, nb = (id / gx) * 32;

    __shared__ float t[32][33];
    const int tx = threadIdx.x & 31, ty = threadIdx.x >> 5;   // ty 0..7
    for (int i = ty; i < 32; i += 8) {
        int k = kb + i, n = nb + tx;
        t[i][tx] = (k < K && n < N) ? W[(size_t)k * N + n] : 0.f;
    }
    __syncthreads();
    for (int i = ty; i < 32; i += 8) {
        int n = nb + i, k = kb + tx;
        if (n < Npad && k < Kpad) Wt[(size_t)n * Kpad + k] = f2bf(t[tx][i]);
    }
}

// ---------------------------------------------------------------------------
// MFMA bf16 GEMM, BK=64 K-tiles (round-21 verified): 8 global_load_lds per
// wave per iter, 16 barriers. Linear LDS [128][64] with XOR involution
// swizzle (chunk ^= row&7) applied at BOTH stage-source and fragment-read.
// MODE 0: fp32 out  2: gelu(x+bias,tanh-form) -> bf16  3: p-gate fp32
// MODE 5: qkvb split -> bf16 q/k/v (col<3072) + sigmoid fp32 beta -> C3
// ---------------------------------------------------------------------------
template<int MODE>
__global__ __launch_bounds__(256)
void mgemm(const unsigned short* __restrict__ A, const unsigned short* __restrict__ A2,
           int Ksplit, int lda1, int lda2,
           const unsigned short* __restrict__ Bt,
           const float* __restrict__ bias, const float* __restrict__ aux,
           void* __restrict__ C0, void* __restrict__ C1, void* __restrict__ C2,
           void* __restrict__ C3,
           int M, int N, int K, int Nout)
{
    __shared__ __align__(16) unsigned short As[128 * 64];
    __shared__ __align__(16) unsigned short Bs[128 * 64];
    const int tid = threadIdx.x;
    const int nwg = gridDim.x * gridDim.y;
    const int bidf = blockIdx.y * gridDim.x + blockIdx.x;
    const int nb = (bidf & 7) * (nwg >> 3) + (bidf >> 3);
    const int m0 = (nb / gridDim.x) * 128, n0 = (nb % gridDim.x) * 128;
    const int l = tid & 63;
    const int wid = tid >> 6;
    const int wr = (tid >> 7) & 1, wc = (tid >> 6) & 1;

    const int srow = l >> 3;                      // row within 8-row group
    const int cgo  = (((l & 7) ^ srow) << 3);     // swizzled source chunk (shorts)
    const int fr = l & 15;

    const f4v zf = {0.f, 0.f, 0.f, 0.f};
    f4v acc[4][4];
#pragma unroll
    for (int i = 0; i < 4; ++i)
#pragma unroll
        for (int j = 0; j < 4; ++j) acc[i][j] = zf;

    const int nkt = K >> 6;
    for (int kt = 0; kt < nkt; ++kt) {
        const int k0 = kt << 6;
#pragma unroll
        for (int j = 0; j < 4; ++j) {
            const int g = wid * 4 + j;            // 16 groups of 8 rows
            const int row = g * 8 + srow;
            const unsigned short* srcA = (k0 < Ksplit)
                ? A  + (size_t)(m0 + row) * lda1 + (size_t)(k0 + cgo)
                : A2 + (size_t)(m0 + row) * lda2 + (size_t)(k0 - Ksplit + cgo);
            __builtin_amdgcn_global_load_lds(
                (const __attribute__((address_space(1))) unsigned int*)srcA,
                (__attribute__((address_space(3))) unsigned int*)&As[g * 512],
                16, 0, 0);
            const unsigned short* srcB = Bt + (size_t)(n0 + row) * K + (size_t)(k0 + cgo);
            __builtin_amdgcn_global_load_lds(
                (const __attribute__((address_space(1))) unsigned int*)srcB,
                (__attribute__((address_space(3))) unsigned int*)&Bs[g * 512],
                16, 0, 0);
        }
        __syncthreads();
#pragma unroll
        for (int ks = 0; ks < 2; ++ks) {
            s8v af[4], bfr[4];
#pragma unroll
            for (int i = 0; i < 4; ++i) {
                const int rowA = wr * 64 + i * 16 + fr;
                const int rowB = wc * 64 + i * 16 + fr;
                const int gch = (l >> 4) + ks * 4;            // global chunk 0..7
                af[i]  = *(const s8v*)&As[rowA * 64 + ((gch ^ (rowA & 7)) << 3)];
                bfr[i] = *(const s8v*)&Bs[rowB * 64 + ((gch ^ (rowB & 7)) << 3)];
            }
#pragma unroll
            for (int i = 0; i < 4; ++i)
#pragma unroll
                for (int j = 0; j < 4; ++j)
                    acc[i][j] = __builtin_amdgcn_mfma_f32_16x16x32_bf16(af[i], bfr[j], acc[i][j], 0, 0, 0);
        }
        __syncthreads();
    }
    const int fq4 = (l >> 4) * 4;
#pragma unroll
    for (int i = 0; i < 4; ++i) {
#pragma unroll
        for (int j = 0; j < 4; ++j) {
            int col = n0 + wc * 64 + j * 16 + fr;
            if (MODE == 3 && col >= Nout) continue;
#pragma unroll
            for (int q = 0; q < 4; ++q) {
                int row = m0 + wr * 64 + i * 16 + fq4 + q;
                float x = acc[i][j][q];
                if (MODE == 2) {
                    x += bias[col];
                    float x3 = x * x * x;
                    float yv = 1.59576912f * fmaf(0.044715f, x3, x);
                    float e = expf(yv);
                    x = x * e / (1.f + e);
                    ((unsigned short*)C0)[(size_t)row * N + col] = f2bf(x);
                } else if (MODE == 3) {
                    x += bias[col];
                    x *= expf(-aux[col >> 2]);
                    x = 0.02f + 0.98f * sigmoidf_(x);
                    ((float*)C0)[(size_t)row * Nout + col] = x;
                } else if (MODE == 5) {
                    if (col < 3072) {
                        unsigned short* dst = (col < 1024) ? (unsigned short*)C0
                                            : ((col < 2048) ? (unsigned short*)C1
                                                            : (unsigned short*)C2);
                        dst[(size_t)row * 1024 + (col & 1023)] = f2bf(x);
                    } else if (col < 3080) {
                        ((float*)C3)[(size_t)row * 8 + (col - 3072)] = sigmoidf_(x);
                    }
                } else {
                    ((float*)C0)[(size_t)row * N + col] = x;
                }
            }
        }
    }
}

// ---------------------------------------------------------------------------
// Short causal conv (K=4) + SiLU, v2 (round-26 verified): 8 rows x 8 chans
// per thread, sliding-window register reuse. Fused q,k,v, non-aliased bufs.
// ---------------------------------------------------------------------------
__global__ __launch_bounds__(256)
void shortconv3(const unsigned short* __restrict__ xq, const unsigned short* __restrict__ xk,
                const unsigned short* __restrict__ xv,
                const float* __restrict__ wq, const float* __restrict__ wk,
                const float* __restrict__ wv,
                unsigned short* __restrict__ yq, unsigned short* __restrict__ yk,
                unsigned short* __restrict__ yv)
{
    const int job = blockIdx.x >> 10;
    const int bx  = blockIdx.x & 1023;
    const unsigned short* x = (job == 0) ? xq : (job == 1) ? xk : xv;
    const float* w          = (job == 0) ? wq : (job == 1) ? wk : wv;
    unsigned short* y       = (job == 0) ? yq : (job == 1) ? yk : yv;

    const int gidx = bx * 256 + threadIdx.x;      // 0..262143
    const int cchunk = gidx & 127;                // channel chunk (coalescing)
    const int rg = gidx >> 7;                     // row-group 0..2047
    const int c0 = cchunk * 8;
    const long r0 = (long)rg * 8;
    const int l0 = (int)(r0 & (LSEQ - 1));        // 0 only at sequence starts

    float4 wv8[8];
#pragma unroll
    for (int e = 0; e < 8; ++e) wv8[e] = ((const float4*)w)[c0 + e];

    const unsigned short* xp = x + r0 * DMODEL + c0;
    const s8v z8 = {0, 0, 0, 0, 0, 0, 0, 0};
    s8v xr[11];
    if (l0 > 0) {
#pragma unroll
        for (int i = 0; i < 11; ++i)
            xr[i] = *(const s8v*)&xp[(long)(i - 3) * DMODEL];
    } else {
        xr[0] = z8; xr[1] = z8; xr[2] = z8;
#pragma unroll
        for (int i = 3; i < 11; ++i)
            xr[i] = *(const s8v*)&xp[(long)(i - 3) * DMODEL];
    }

    unsigned short* yp = y + r0 * DMODEL + c0;
#pragma unroll
    for (int r = 0; r < 8; ++r) {
        float acc[8] = {0.f, 0.f, 0.f, 0.f, 0.f, 0.f, 0.f, 0.f};
#pragma unroll
        for (int j = 0; j < 4; ++j) {
            s8v v = xr[r + j];
#pragma unroll
            for (int e = 0; e < 8; ++e)
                acc[e] = fmaf(bf2f((unsigned short)v[e]), (&wv8[e].x)[j], acc[e]);
        }
        s8v o;
#pragma unroll
        for (int e = 0; e < 8; ++e) {
            float yv2 = acc[e] * sigmoidf_(acc[e]);
            o[e] = (short)f2bf(yv2);
        }
        *(s8v*)&yp[(long)r * DMODEL] = o;
    }
}

// ---------------------------------------------------------------------------
// Phase 1 prep (round-15 verified: blocked LDS solve, kn row write-through)
// ---------------------------------------------------------------------------
__global__ __launch_bounds__(256)
void chunk_prep3(const unsigned short* __restrict__ qconv, const unsigned short* __restrict__ kconv,
                 const unsigned short* __restrict__ vbf, const float* __restrict__ beta,
                 unsigned short* __restrict__ qe_out, unsigned short* __restrict__ kn_out,
                 bf16* __restrict__ wu, unsigned short* __restrict__ opre)
{
    const int bid = blockIdx.x;              // (b*8+h)*128 + c
    const int c = bid & 127, h = (bid >> 7) & 7, b = bid >> 10;
    const int tid = threadIdx.x;
    const int l = tid & 63, wid = tid >> 6;

    __shared__ __align__(16) unsigned short q_b[32 * 136];
    __shared__ __align__(16) unsigned short k_b[32 * 136];
    __shared__ __align__(16) unsigned short at_b[32 * 40];
    __shared__ float xs[32][257];            // solve state: [row][column(tid)]
    __shared__ __align__(16) float Am[32][36];
    __shared__ float betas_s[32];

    const size_t row0 = (size_t)b * LSEQ + (size_t)c * 32;
    const size_t base = row0 * DMODEL + (size_t)h * DHEAD;
    const f4v zf = {0.f, 0.f, 0.f, 0.f};
    const int li = tid >> 3, ld0 = (tid & 7) * 16;

    // ---- phase 0: load q,k rows (bf16, vectorized)
    {
        const unsigned short* gq = qconv + base + (size_t)li * DMODEL + ld0;
        const unsigned short* gk = kconv + base + (size_t)li * DMODEL + ld0;
        *(uint4*)&q_b[li * 136 + ld0]     = ((const uint4*)gq)[0];
        *(uint4*)&q_b[li * 136 + ld0 + 8] = ((const uint4*)gq)[1];
        *(uint4*)&k_b[li * 136 + ld0]     = ((const uint4*)gk)[0];
        *(uint4*)&k_b[li * 136 + ld0 + 8] = ((const uint4*)gk)[1];
    }
    if (tid < 32) betas_s[tid] = beta[(row0 + tid) * NHEAD + h];
    __syncthreads();

    // ---- phase 1: l2norm rows of q,k (re-read LDS)
    {
        float sq = 0.f, sk = 0.f;
#pragma unroll
        for (int e = 0; e < 8; ++e) {
            unsigned uq = *(const unsigned*)&q_b[li * 136 + ld0 + e * 2];
            unsigned uk = *(const unsigned*)&k_b[li * 136 + ld0 + e * 2];
            float q0 = bf2f((unsigned short)uq), q1 = bf2f((unsigned short)(uq >> 16));
            float k0 = bf2f((unsigned short)uk), k1 = bf2f((unsigned short)(uk >> 16));
            sq = fmaf(q0, q0, fmaf(q1, q1, sq));
            sk = fmaf(k0, k0, fmaf(k1, k1, sk));
        }
#pragma unroll
        for (int m = 1; m < 8; m <<= 1) { sq += __shfl_xor(sq, m); sk += __shfl_xor(sk, m); }
        float rq = rsqrtf(sq + 1e-6f), rk = rsqrtf(sk + 1e-6f);
#pragma unroll
        for (int e = 0; e < 8; ++e) {
            unsigned uq = *(const unsigned*)&q_b[li * 136 + ld0 + e * 2];
            unsigned uk = *(const unsigned*)&k_b[li * 136 + ld0 + e * 2];
            unsigned pq = (unsigned)f2bf(bf2f((unsigned short)uq) * rq)
                        | ((unsigned)f2bf(bf2f((unsigned short)(uq >> 16)) * rq) << 16);
            unsigned pk = (unsigned)f2bf(bf2f((unsigned short)uk) * rk)
                        | ((unsigned)f2bf(bf2f((unsigned short)(uk >> 16)) * rk) << 16);
            *(unsigned*)&q_b[li * 136 + ld0 + e * 2] = pq;
            *(unsigned*)&k_b[li * 136 + ld0 + e * 2] = pk;
        }
    }
    __syncthreads();

    // ---- phase 2: kn write-through (vectorized)
    {
        unsigned short* gk = kn_out + base + (size_t)li * DMODEL + ld0;
        ((uint4*)gk)[0] = *(const uint4*)&k_b[li * 136 + ld0];
        ((uint4*)gk)[1] = *(const uint4*)&k_b[li * 136 + ld0 + 8];
    }

    // ---- phase 3: Am, at via MFMA (wave wid -> 16x16 tile (tr,tc))
    {
        const int tr = wid >> 1, tc = wid & 1;
        const int fr = l & 15, ko = (l >> 4) * 8;
        f4v accA = zf, accT = zf;
#pragma unroll
        for (int kt = 0; kt < 4; ++kt) {
            s8v ka  = *(const s8v*)&k_b[(tr * 16 + fr) * 136 + kt * 32 + ko];
            s8v qa  = *(const s8v*)&q_b[(tr * 16 + fr) * 136 + kt * 32 + ko];
            s8v kb2 = *(const s8v*)&k_b[(tc * 16 + fr) * 136 + kt * 32 + ko];
            accA = __builtin_amdgcn_mfma_f32_16x16x32_bf16(ka, kb2, accA, 0, 0, 0);
            accT = __builtin_amdgcn_mfma_f32_16x16x32_bf16(qa, kb2, accT, 0, 0, 0);
        }
        const int jloc = tc * 16 + fr;
#pragma unroll
        for (int q = 0; q < 4; ++q) {
            int iloc = tr * 16 + (l >> 4) * 4 + q;
            Am[iloc][jloc] = (iloc > jloc) ? betas_s[iloc] * accA[q] : 0.f;
            at_b[iloc * 40 + jloc] = f2bf((iloc >= jloc) ? accT[q] : 0.f);
        }
    }
    __syncthreads();

    // ---- phase 4: blocked forward substitution; thread t = one column.
    {
        const int t = tid;
        if (t < 128) {
#pragma unroll 1
            for (int i = 0; i < 32; ++i)
                xs[i][t] = betas_s[i] * bf2f(vbf[base + (size_t)i * DMODEL + t]);
        } else {
            const int d = t - 128;
#pragma unroll 1
            for (int i = 0; i < 32; ++i)
                xs[i][t] = betas_s[i] * bf2f(k_b[i * 136 + d]);
        }
#pragma unroll 1
        for (int b8 = 0; b8 < 4; ++b8) {
            const int i0 = b8 * 8;
            float xl[8];
#pragma unroll
            for (int j = 0; j < 8; ++j) xl[j] = xs[i0 + j][t];
            // apply previous blocks
#pragma unroll 1
            for (int m = 0; m < i0; m += 4) {
                float xm0 = xs[m][t],     xm1 = xs[m + 1][t];
                float xm2 = xs[m + 2][t], xm3 = xs[m + 3][t];
#pragma unroll
                for (int j = 0; j < 8; ++j) {
                    float4 am = *(const float4*)&Am[i0 + j][m];
                    xl[j] -= am.x * xm0 + am.y * xm1 + am.z * xm2 + am.w * xm3;
                }
            }
            // in-register 8x8 triangle
#pragma unroll
            for (int j = 1; j < 8; ++j) {
                float s = 0.f;
#pragma unroll
                for (int jj = 0; jj < j; ++jj) s = fmaf(Am[i0 + j][i0 + jj], xl[jj], s);
                xl[j] -= s;
            }
#pragma unroll
            for (int j = 0; j < 8; ++j) xs[i0 + j][t] = xl[j];
        }
        // global w|u writeback (reads own column: conflict-free)
        const size_t tb = (size_t)bid * 8192;
        if (t < 128) {
#pragma unroll 1
            for (int i = 0; i < 32; ++i)
                wu[tb + 4096 + i * 128 + t] = __float2bfloat16(xs[i][t]);
        } else {
            const int d = t - 128;
#pragma unroll 1
            for (int i = 0; i < 32; ++i)
                wu[tb + i * 128 + d] = __float2bfloat16(xs[i][t]);
        }
    }
    __syncthreads();

    // ---- phase 5: qe = qn - at@w ; o_pre = at@u (B-fragments built from xs)
    {
        const int fr = l & 15, ko = (l >> 4) * 8;
        s8v bw0, bw1, bu0, bu1;
#pragma unroll
        for (int e = 0; e < 8; ++e) {
            bw0[e] = (short)f2bf(xs[ko + e][128 + wid * 32 + fr]);
            bw1[e] = (short)f2bf(xs[ko + e][128 + wid * 32 + 16 + fr]);
            bu0[e] = (short)f2bf(xs[ko + e][wid * 32 + fr]);
            bu1[e] = (short)f2bf(xs[ko + e][wid * 32 + 16 + fr]);
        }
#pragma unroll
        for (int rt = 0; rt < 2; ++rt) {
            s8v a = *(const s8v*)&at_b[(rt * 16 + fr) * 40 + ko];
            f4v qw0 = __builtin_amdgcn_mfma_f32_16x16x32_bf16(a, bw0, zf, 0, 0, 0);
            f4v qw1 = __builtin_amdgcn_mfma_f32_16x16x32_bf16(a, bw1, zf, 0, 0, 0);
            f4v ou0 = __builtin_amdgcn_mfma_f32_16x16x32_bf16(a, bu0, zf, 0, 0, 0);
            f4v ou1 = __builtin_amdgcn_mfma_f32_16x16x32_bf16(a, bu1, zf, 0, 0, 0);
#pragma unroll
            for (int q = 0; q < 4; ++q) {
                const int i = rt * 16 + (l >> 4) * 4 + q;
                {
                    const int d = wid * 32 + fr;
                    size_t g = base + (size_t)i * DMODEL + d;
                    qe_out[g] = f2bf(bf2f(q_b[i * 136 + d]) - qw0[q]);
                    opre[g]   = f2bf(ou0[q]);
                }
                {
                    const int d = wid * 32 + 16 + fr;
                    size_t g = base + (size_t)i * DMODEL + d;
                    qe_out[g] = f2bf(bf2f(q_b[i * 136 + d]) - qw1[q]);
                    opre[g]   = f2bf(ou1[q]);
                }
            }
        }
    }
}

// ---------------------------------------------------------------------------
// Phase 2: MFMA state scan, 8 waves (512 thr), role-split (round-19/21
// verified best). knT transpose write uses compile-time e indexing +
// pcolp XOR swizzle; phase-B read compensates with koff^sw.
// ---------------------------------------------------------------------------
__global__ __launch_bounds__(512)
void delta_scan5(const unsigned short* __restrict__ qe, const unsigned short* __restrict__ kn,
                 const bf16* __restrict__ wu, bf16* __restrict__ delta,
                 const float* __restrict__ ret)
{
    const int bid0 = blockIdx.x;
    const int dvs = (bid0 >> 3) & 7;                      // dv-slice
    const int bh  = ((bid0 >> 6) << 3) | (bid0 & 7);      // xcd-stable bh
    const int h = bh & 7, b = bh >> 3;
    const int tid = threadIdx.x;
    const int l = tid & 63, wid = tid >> 6;

    __shared__ __align__(16) unsigned short qe_b[2][32 * 136];
    __shared__ __align__(16) unsigned short w_b [2][32 * 136];
    __shared__ __align__(16) unsigned short knT [2][128 * 40];
    __shared__ __align__(16) unsigned short St_b[16 * 136];
    __shared__ __align__(16) unsigned short uaT [16 * 40];
    __shared__ float us_s[2][32][18], ops_s[2][32][18];

    const float lam = 0.6f + 0.4f * sigmoidf_(ret[h]);

    for (int i = tid; i < 16 * 136; i += 512) St_b[i] = 0;

    // producer-thread geometry (tid >= 256)
    const int pti = tid & 255;
    const int pli = pti >> 3, pld0 = (pti & 7) * 16;
    const int piu = pti >> 3, ptu = (pti & 7) * 2;
    const int pkswz = ((pld0 >> 4) & 3) << 3;
    const int pcolp = pli ^ pkswz;
    const size_t headoff = (size_t)h * DHEAD;

    const f4v zf = {0.f, 0.f, 0.f, 0.f};
    f4v Sacc = zf;                      // this wave's S d-tile (d0 = wid*16)

    uint4 pq[2], pk[2], pw[2];
    unsigned puv, pov;

#define ISSUE(cc)  {                                                                        \
        size_t rb = ((size_t)b * LSEQ + (size_t)(cc) * 32);                                 \
        const unsigned short* gq = qe + (rb + pli) * DMODEL + headoff + pld0;               \
        const unsigned short* gk = kn + (rb + pli) * DMODEL + headoff + pld0;               \
        pq[0] = ((const uint4*)gq)[0]; pq[1] = ((const uint4*)gq)[1];                       \
        pk[0] = ((const uint4*)gk)[0]; pk[1] = ((const uint4*)gk)[1];                       \
        size_t tb = ((size_t)bh * NCHUNK + (cc)) * 8192;                                    \
        const uint4* gw = (const uint4*)(wu + tb + pli * 128 + pld0);                       \
        pw[0] = gw[0]; pw[1] = gw[1];                                                       \
        puv = *(const unsigned*)(wu + tb + 4096 + piu * 128 + dvs * 16 + ptu);              \
        pov = *(const unsigned*)(delta + (rb + piu) * DMODEL + headoff + dvs * 16 + ptu);   \
    }

#define UNPACK(bf)  {                                                                       \
        *(uint4*)&qe_b[bf][pli * 136 + pld0]     = pq[0];                                   \
        *(uint4*)&qe_b[bf][pli * 136 + pld0 + 8] = pq[1];                                   \
        const unsigned short* pks = (const unsigned short*)&pk[0];                          \
        _Pragma("unroll")                                                                   \
        for (int e = 0; e < 16; ++e)                                                        \
            knT[bf][(pld0 + e) * 40 + pcolp] = pks[e];                                      \
        *(uint4*)&w_b[bf][pli * 136 + pld0]     = pw[0];                                    \
        *(uint4*)&w_b[bf][pli * 136 + pld0 + 8] = pw[1];                                    \
        us_s[bf][piu][ptu]      = bf2f((unsigned short)puv);                                \
        us_s[bf][piu][ptu + 1]  = bf2f((unsigned short)(puv >> 16));                        \
        ops_s[bf][piu][ptu]     = bf2f((unsigned short)pov);                                \
        ops_s[bf][piu][ptu + 1] = bf2f((unsigned short)(pov >> 16));                        \
    }

    if (tid >= 256) {
        ISSUE(0);
        UNPACK(0);
        ISSUE(1);
    }
    __syncthreads();

    for (int c = 0; c < NCHUNK; ++c) {
        const int cur = c & 1;

        if (wid < 4) {
            // ---- phase A (consumers): w0,w1 -> ua = u - w@S ; w2,w3 -> o = opre + qe@S
            const int half = wid & 1;
            const int arow = half * 16 + (l & 15);
            const int koff = (l >> 4) * 8;
            const unsigned short* ab = (wid < 2) ? w_b[cur] : qe_b[cur];
            f4v a0v = zf, a1v = zf;
#pragma unroll
            for (int kt = 0; kt < 2; ++kt) {
                s8v af  = *(const s8v*)&ab[arow * 136 + kt * 32 + koff];
                s8v bf_ = *(const s8v*)&St_b[(l & 15) * 136 + kt * 32 + koff];
                a0v = __builtin_amdgcn_mfma_f32_16x16x32_bf16(af, bf_, a0v, 0, 0, 0);
            }
#pragma unroll
            for (int kt = 2; kt < 4; ++kt) {
                s8v af  = *(const s8v*)&ab[arow * 136 + kt * 32 + koff];
                s8v bf_ = *(const s8v*)&St_b[(l & 15) * 136 + kt * 32 + koff];
                a1v = __builtin_amdgcn_mfma_f32_16x16x32_bf16(af, bf_, a1v, 0, 0, 0);
            }
            const int ib = half * 16 + ((l >> 4) << 2);
            const int t = l & 15;
            if (wid < 2) {
#pragma unroll
                for (int q = 0; q < 4; ++q) {
                    float v = us_s[cur][ib + q][t] - (a0v[q] + a1v[q]);
                    uaT[t * 40 + ib + q] = f2bf(v);
                }
            } else {
                size_t rb = (size_t)b * LSEQ + (size_t)c * 32;
#pragma unroll
                for (int q = 0; q < 4; ++q) {
                    float v = ops_s[cur][ib + q][t] + (a0v[q] + a1v[q]);
                    delta[(rb + ib + q) * DMODEL + headoff + dvs * 16 + t] = __float2bfloat16(v);
                }
            }
        } else {
            // ---- producers: prefetch next chunk into the other buffer
            if (c + 1 < NCHUNK) UNPACK(cur ^ 1);
            if (c + 2 < NCHUNK) ISSUE(c + 2);
        }
        __syncthreads();

        // ---- phase B (all 8 waves): Sacc = lam*Sacc + uaT @ knT ; export St_b
        {
#pragma unroll
            for (int q = 0; q < 4; ++q) Sacc[q] *= lam;
            const int koff = (l >> 4) * 8;
            const int sw = (wid & 3) << 3;         // (d>>4)&3 for d = wid*16+(l&15)
            s8v af = *(const s8v*)&uaT[(l & 15) * 40 + koff];
            const int d0 = wid * 16;
            s8v b0 = *(const s8v*)&knT[cur][(d0 + (l & 15)) * 40 + (koff ^ sw)];
            Sacc = __builtin_amdgcn_mfma_f32_16x16x32_bf16(af, b0, Sacc, 0, 0, 0);

            const int tr = (l >> 4) << 2;
#pragma unroll
            for (int q = 0; q < 4; ++q)
                St_b[(tr + q) * 136 + d0 + (l & 15)] = f2bf(Sacc[q]);
        }
        __syncthreads();
    }
#undef ISSUE
#undef UNPACK
}

// ---------------------------------------------------------------------------
// FIR computed once, LDS-tiled (round-27 verified, stats NOT fused)
// ---------------------------------------------------------------------------
__global__ __launch_bounds__(256)
void fir_compute(const unsigned short* __restrict__ v,
                 const float* __restrict__ wshort, const float* __restrict__ wlong,
                 unsigned short* __restrict__ fso, unsigned short* __restrict__ flo)
{
    const int lt = blockIdx.x, h = blockIdx.y, b = blockIdx.z;
    const int tid = threadIdx.x;
    __shared__ unsigned short vt[190 * 128];
    __shared__ float wl[63 * 128];
    __shared__ float w3[3 * 128];

    for (int i = tid; i < 63 * 128; i += 256) {
        int j = i >> 7, d = i & 127;
        wl[i] = wlong[((size_t)h * 128 + d) * 63 + j];
    }
    for (int i = tid; i < 3 * 128; i += 256) {
        int j = i >> 7, d = i & 127;
        w3[i] = wshort[((size_t)h * 128 + d) * 3 + j];
    }
    const size_t vbase = ((size_t)b * LSEQ) * DMODEL + (size_t)h * DHEAD;
    const int l0 = lt * 128;
    const s8v z8 = {0, 0, 0, 0, 0, 0, 0, 0};
    for (int i = tid; i < 190 * 16; i += 256) {
        int row = i >> 4, dblk = (i & 15) * 8;
        int gl = l0 - 62 + row;
        s8v val = z8;
        if (gl >= 0) val = *(const s8v*)&v[vbase + (size_t)gl * DMODEL + dblk];
        *(s8v*)&vt[row * 128 + dblk] = val;
    }
    __syncthreads();

    const int dp = (tid & 63) * 2, lg = tid >> 6;
    for (int lc = 0; lc < 4; ++lc) {
        const int lb = lg * 32 + lc * 8;
        float a0[8], a1[8], s0[8], s1[8];
#pragma unroll
        for (int li = 0; li < 8; ++li) { a0[li] = a1[li] = s0[li] = s1[li] = 0.f; }
        for (int j = 0; j < 63; ++j) {
            float w0 = wl[j * 128 + dp], w1 = wl[j * 128 + dp + 1];
#pragma unroll
            for (int li = 0; li < 8; ++li) {
                unsigned vv = *(const unsigned*)&vt[(lb + li + j) * 128 + dp];
                a0[li] = fmaf(bf2f((unsigned short)vv), w0, a0[li]);
                a1[li] = fmaf(bf2f((unsigned short)(vv >> 16)), w1, a1[li]);
            }
        }
#pragma unroll
        for (int j = 0; j < 3; ++j) {
            float w0 = w3[j * 128 + dp], w1 = w3[j * 128 + dp + 1];
#pragma unroll
            for (int li = 0; li < 8; ++li) {
                unsigned vv = *(const unsigned*)&vt[(lb + li + 60 + j) * 128 + dp];
                s0[li] = fmaf(bf2f((unsigned short)vv), w0, s0[li]);
                s1[li] = fmaf(bf2f((unsigned short)(vv >> 16)), w1, s1[li]);
            }
        }
        const size_t ob = ((size_t)b * LSEQ + l0) * DMODEL + (size_t)h * DHEAD + dp;
#pragma unroll
        for (int li = 0; li < 8; ++li) {
            unsigned pf = (unsigned)f2bf(a0[li]) | ((unsigned)f2bf(a1[li]) << 16);
            unsigned ps = (unsigned)f2bf(s0[li]) | ((unsigned)f2bf(s1[li]) << 16);
            *(unsigned*)&flo[ob + (size_t)(lb + li) * DMODEL] = pf;
            *(unsigned*)&fso[ob + (size_t)(lb + li) * DMODEL] = ps;
        }
    }
}

// ---------------------------------------------------------------------------
// Stats: one wave per (r,h) row; bf16 output at stride 64 (cols 32..63 unused)
// ---------------------------------------------------------------------------
__global__ __launch_bounds__(256)
void fir_stats2(const unsigned short* __restrict__ fs, const unsigned short* __restrict__ fl,
                const unsigned short* __restrict__ dlt, const unsigned short* __restrict__ v,
                unsigned short* __restrict__ stats)
{
    const int rh = blockIdx.x * 4 + (threadIdx.x >> 6);
    const int lane = threadIdx.x & 63;
    const int r = rh >> 3, h = rh & 7;
    const size_t base = (size_t)r * DMODEL + (size_t)h * DHEAD + lane * 2;
    unsigned ua = *(const unsigned*)(fs + base);
    unsigned ub = *(const unsigned*)(fl + base);
    unsigned uc = *(const unsigned*)(dlt + base);
    unsigned ud = *(const unsigned*)(v + base);
    float s0 = bf2f((unsigned short)ua) + bf2f((unsigned short)(ua >> 16));
    float s1 = bf2f((unsigned short)ub) + bf2f((unsigned short)(ub >> 16));
    float s2 = bf2f((unsigned short)uc) + bf2f((unsigned short)(uc >> 16));
    float s3 = bf2f((unsigned short)ud) + bf2f((unsigned short)(ud >> 16));
#pragma unroll
    for (int m = 1; m < 64; m <<= 1) {
        s0 += __shfl_xor(s0, m); s1 += __shfl_xor(s1, m);
        s2 += __shfl_xor(s2, m); s3 += __shfl_xor(s3, m);
    }
    if (lane == 0) {
        const float inv = 1.f / 128.f;
        stats[(size_t)r * 64 + 0  + h] = f2bf(s0 * inv);
        stats[(size_t)r * 64 + 8  + h] = f2bf(s1 * inv);
        stats[(size_t)r * 64 + 16 + h] = f2bf(s2 * inv);
        stats[(size_t)r * 64 + 24 + h] = f2bf(s3 * inv);
    }
}

// ---------------------------------------------------------------------------
// Combine + RMS norm; bf16 output (feeds final MFMA GEMM)
// ---------------------------------------------------------------------------
__global__ __launch_bounds__(256)
void combine2(const unsigned short* __restrict__ fs, const unsigned short* __restrict__ fl,
              const unsigned short* __restrict__ dlt, const unsigned short* __restrict__ v,
              const float* __restrict__ p, const float* __restrict__ onw,
              unsigned short* __restrict__ on)
{
    const int rh = blockIdx.x * 4 + (threadIdx.x >> 6);
    const int lane = threadIdx.x & 63;
    const int r = rh >> 3, h = rh & 7;
    const size_t base = (size_t)r * DMODEL + (size_t)h * DHEAD + lane * 2;
    unsigned ua = *(const unsigned*)(fs + base);
    unsigned ub = *(const unsigned*)(fl + base);
    unsigned uc = *(const unsigned*)(dlt + base);
    unsigned ud = *(const unsigned*)(v + base);
    const float* pp = p + (size_t)r * 32 + h * 4;
    float p0 = pp[0], p1 = pp[1], p2 = pp[2], p3 = pp[3];
    float ox = p0 * bf2f((unsigned short)ua) + p1 * bf2f((unsigned short)ub)
             + p2 * bf2f((unsigned short)uc) + p3 * bf2f((unsigned short)ud);
    float oy = p0 * bf2f((unsigned short)(ua >> 16)) + p1 * bf2f((unsigned short)(ub >> 16))
             + p2 * bf2f((unsigned short)(uc >> 16)) + p3 * bf2f((unsigned short)(ud >> 16));
    float ss = ox * ox + oy * oy;
#pragma unroll
    for (int m = 1; m < 64; m <<= 1) ss += __shfl_xor(ss, m);
    float sc = rsqrtf(ss * (1.f / 128.f) + 1e-5f);
    unsigned pw = (unsigned)f2bf(ox * sc * onw[lane * 2])
                | ((unsigned)f2bf(oy * sc * onw[lane * 2 + 1]) << 16);
    *(unsigned*)(on + base) = pw;
}

// ---------------------------------------------------------------------------
// Workspace (~203 MB), RACE-FREE. hdn spans B.hi+C.lo (contiguous 64MB);
// onb in B.hi after hdn dies.
//  A.lo: qpb -> wu.lo -> fs          A.hi: kpb -> wu.hi -> fl
//  B.lo: vpb -> opre/delta           B.hi: qcb/qe -> hdn[0:8192) -> o_norm
//  C.lo: kcb/kn -> hdn[8192:16384)   C.hi: vbf (lives to combine)
//  O.lo(d_out): hsb bf16             O.hi: wqkvbt  -> final out fp32 (full)
// ---------------------------------------------------------------------------
extern "C" void kernel_launch(void* const* d_in, const int* in_sizes, int n_in,
                              void* d_out, int out_size, void* d_ws, size_t ws_size,
                              hipStream_t stream)
{
    const float* hs   = (const float*)d_in[0];
    const float* Wq   = (const float*)d_in[1];
    const float* Wk   = (const float*)d_in[2];
    const float* Wv   = (const float*)d_in[3];
    const float* Wb   = (const float*)d_in[4];
    const float* cqw  = (const float*)d_in[5];
    const float* ckw  = (const float*)d_in[6];
    const float* cvw  = (const float*)d_in[7];
    const float* ret  = (const float*)d_in[8];
    const float* fsw  = (const float*)d_in[9];
    const float* flw  = (const float*)d_in[10];
    const float* gw1  = (const float*)d_in[11];
    const float* gb1  = (const float*)d_in[12];
    const float* gw2  = (const float*)d_in[13];
    const float* gb2  = (const float*)d_in[14];
    const float* ltmp = (const float*)d_in[15];
    const float* onw  = (const float*)d_in[16];
    const float* Wo   = (const float*)d_in[17];
    float* out = (float*)d_out;

    char* wsp = (char*)d_ws;
    size_t off = 0;
    auto alloc = [&](size_t nbytes) -> void* {
        void* pt = (void*)(wsp + off);
        off += ((nbytes + 255) / 256) * 256;
        return pt;
    };
    const int R = R_TOT;
    const size_t HALF = (size_t)R * DMODEL;        // elements per 32MB half
    float* bufA  = (float*)alloc(HALF * 4);
    float* bufB  = (float*)alloc(HALF * 4);
    float* bufC  = (float*)alloc(HALF * 4);
    float* beta  = (float*)alloc((size_t)R * NHEAD * 4);
    unsigned short* statsb = (unsigned short*)alloc((size_t)R * 64 * 2);
    float* pbuf  = (float*)alloc((size_t)R * 32 * 4);
    unsigned short* gw1t = (unsigned short*)alloc((size_t)2048 * 1088 * 2);
    unsigned short* wot  = (unsigned short*)alloc((size_t)1024 * 1024 * 2);
    unsigned short* gw2t = (unsigned short*)alloc((size_t)128 * 2048 * 2);

    unsigned short* Alo = (unsigned short*)bufA;  unsigned short* Ahi = Alo + HALF;
    unsigned short* Blo = (unsigned short*)bufB;  unsigned short* Bhi = Blo + HALF;
    unsigned short* Clo = (unsigned short*)bufC;  unsigned short* Chi = Clo + HALF;
    unsigned short* Olo = (unsigned short*)d_out; unsigned short* Ohi = Olo + HALF;

    unsigned short* hsb    = Olo;                 // hs bf16
    unsigned short* wqkvbt = Ohi;                 // 3200x1024 bf16 = 6.6MB
    unsigned short* qpb = Alo, *kpb = Ahi, *vpb = Blo;
    unsigned short* qcb = Bhi, *kcb = Clo, *vbf = Chi;   // conv out: no aliasing
    bf16* wu = (bf16*)bufA;                       // qpb/kpb dead after conv
    unsigned short* dlt = Blo;                    // opre -> delta (vpb dead)
    unsigned short* fsb = Alo, *flb = Ahi;        // wu dead after scan
    unsigned short* hdnb = Bhi;                   // gate1 out: 64MB span B.hi+C.lo
    unsigned short* onb = Bhi;                    // o_norm bf16 (hdn dead after gate2)
    (void)ws_size; (void)in_sizes; (void)n_in; (void)out_size;

    dim3 blk(256);
    // 0+1. hs cast + all weight transposes in ONE launch (14848 blocks)
    prep_inputs<<<14848, blk, 0, stream>>>(hs, hsb, Wq, Wk, Wv, Wb, gw1, Wo, gw2,
                                           wqkvbt, gw1t, wot, gw2t);

    // 2. fused qkv+beta projection (bf16 A; q/k/v bf16, beta fp32 via C3)
    mgemm<5><<<dim3(25, 128), blk, 0, stream>>>(hsb, nullptr, 1 << 30, DMODEL, 0,
                                                wqkvbt, nullptr, nullptr,
                                                qpb, kpb, vpb, beta, R, 3200, 1024, 0);
    // 4. short conv + silu v2 (8 rows/thread sliding window; 3x1024 blocks)
    shortconv3<<<3 * 1024, blk, 0, stream>>>(qpb, kpb, vpb, cqw, ckw, cvw,
                                             qcb, kcb, vbf);
    // 5/6. delta rule (scan 8-wave role-split)
    chunk_prep3<<<4096, blk, 0, stream>>>(qcb, kcb, vbf, beta, qcb, kcb, wu, dlt);
    delta_scan5<<<256, dim3(512), 0, stream>>>(qcb, kcb, wu, (bf16*)dlt, ret);
    // 7. FIR once (wu dead -> bufA holds fs|fl)
    fir_compute<<<dim3(32, 8, 4), blk, 0, stream>>>(vbf, fsw, flw, fsb, flb);
    // 8. stats (wide grid, one wave per row-head; stride 64)
    fir_stats2<<<32768, blk, 0, stream>>>(fsb, flb, dlt, vbf, statsb);
    // 9. gate MLP, single launch each (hdn = 64MB contiguous B.hi+C.lo)
    mgemm<2><<<dim3(16, 128), blk, 0, stream>>>(hsb, statsb,
                                                1024, DMODEL, 64, gw1t, gb1, nullptr,
                                                hdnb, nullptr, nullptr, nullptr,
                                                R, 2048, 1088, 0);
    mgemm<3><<<dim3(1, 128), blk, 0, stream>>>(hdnb, nullptr, 1 << 30, 2048, 0,
                                               gw2t, gb2, ltmp,
                                               pbuf, nullptr, nullptr, nullptr,
                                               R, 128, 2048, 32);
    // 10. combine + RMS norm -> o_norm bf16 (B.hi; hdn dead after gate2)
    combine2<<<32768, blk, 0, stream>>>(fsb, flb, dlt, vbf, pbuf, onw, onb);
    // 11. final projection -> d_out fp32 (hsb/wqkvbt dead)
    mgemm<0><<<dim3(8, 128), blk, 0, stream>>>(onb, nullptr, 1 << 30, DMODEL, 0,
                                               wot, nullptr, nullptr,
                                               out, nullptr, nullptr, nullptr, R, 1024, 1024, 0);
}